// Round 8
// baseline (282.371 us; speedup 1.0000x reference)
//
#include <hip/hip_runtime.h>
#include <cstdint>
#include <cstddef>

#define DEVI __device__ __forceinline__

typedef __attribute__((ext_vector_type(8))) short short8;
typedef __attribute__((ext_vector_type(4))) float f32x4;

constexpr int Bc = 8, Tc = 2048, Cc = 1024;
constexpr int WKV_L = 32, WKV_NCH = 64;   // T = L * NCH

DEVI unsigned short f2b(float f) {
  unsigned int u = __float_as_uint(f);
  unsigned int r = (u + 0x7FFFu + ((u >> 16) & 1u)) >> 16;  // RNE
  return (unsigned short)r;
}
DEVI float b2f(unsigned short u) {
  return __uint_as_float(((unsigned int)u) << 16);
}

DEVI void gload16(const unsigned short* g, unsigned short* l) {
  __builtin_amdgcn_global_load_lds(
      (const __attribute__((address_space(1))) void*)g,
      (__attribute__((address_space(3))) void*)l, 16, 0, 0);
}

#define FENCE() asm volatile("" ::: "memory")

// ---------------- f32 -> bf16 convert (all 4 weights, one dispatch) --------
__global__ void convert4_kernel(const float* __restrict__ W0,
                                const float* __restrict__ W1,
                                const float* __restrict__ W2,
                                const float* __restrict__ W3,
                                unsigned short* __restrict__ o0,
                                unsigned short* __restrict__ o1,
                                unsigned short* __restrict__ o2,
                                unsigned short* __restrict__ o3) {
  const int i = blockIdx.x * blockDim.x + threadIdx.x;   // [0, CC/4)
  const int s = blockIdx.y;
  const float* in = s == 0 ? W0 : (s == 1 ? W1 : (s == 2 ? W2 : W3));
  unsigned short* out = s == 0 ? o0 : (s == 1 ? o1 : (s == 2 ? o2 : o3));
  const float4 v = ((const float4*)in)[i];
  ushort4 o;
  o.x = f2b(v.x); o.y = f2b(v.y); o.z = f2b(v.z); o.w = f2b(v.w);
  ((ushort4*)out)[i] = o;
}

// ---------------- time-mix (k,v,r) + bf16 cast ----------------
__global__ void mix3_kernel(const float* __restrict__ x,
                            const float* __restrict__ tmk,
                            const float* __restrict__ tmv,
                            const float* __restrict__ tmr,
                            unsigned short* __restrict__ kin,
                            unsigned short* __restrict__ vin,
                            unsigned short* __restrict__ rin,
                            long n4) {
  long i = (long)blockIdx.x * blockDim.x + threadIdx.x;
  const long stride = (long)gridDim.x * blockDim.x;
  for (; i < n4; i += stride) {
    const long e = i * 4;
    const int c = (int)(e & (Cc - 1));
    const long bt = e >> 10;
    const int t = (int)(bt & (Tc - 1));
    const float4 xv = *(const float4*)(x + e);
    float4 pv = {0.f, 0.f, 0.f, 0.f};
    if (t > 0) pv = *(const float4*)(x + e - Cc);
    const float4 mk = *(const float4*)(tmk + c);
    const float4 mv = *(const float4*)(tmv + c);
    const float4 mr = *(const float4*)(tmr + c);
    const float* xp = (const float*)&xv;
    const float* pp = (const float*)&pv;
    const float* mkp = (const float*)&mk;
    const float* mvp = (const float*)&mv;
    const float* mrp = (const float*)&mr;
    ushort4 ko, vo, ro;
    unsigned short* kop = (unsigned short*)&ko;
    unsigned short* vop = (unsigned short*)&vo;
    unsigned short* rop = (unsigned short*)&ro;
#pragma unroll
    for (int q = 0; q < 4; ++q) {
      kop[q] = f2b(xp[q] * mkp[q] + pp[q] * (1.f - mkp[q]));
      vop[q] = f2b(xp[q] * mvp[q] + pp[q] * (1.f - mvp[q]));
      rop[q] = f2b(xp[q] * mrp[q] + pp[q] * (1.f - mrp[q]));
    }
    *(ushort4*)(kin + e) = ko;
    *(ushort4*)(vin + e) = vo;
    *(ushort4*)(rin + e) = ro;
  }
}

// ---- 256x256 / BK=32 / 8-wave GEMM, 4 LDS buffers, counted vmcnt (T4) ----
// C[M][N] = A[M][K] * W[N][K]^T. blockIdx.z selects (A,W,C) triple.
// Per iter: vmcnt(8) [tiles t+1,t+2 stay in flight - NEVER drained];
// ONE barrier; STAGE(t+3); 12 ds_reads; 32 MFMA (setprio). Single barrier
// per iter lets waves slip out of phase -> DS pipe overlaps MFMA pipe.
// Swizzle (row = 64B = 4 slots of 16B): phys slot = s ^ ((row>>1)&3),
// applied on pre-swizzled global source + same involution on read (2-way,
// free). Buffer-reuse safety: tile t-1's reads are register-consumed before
// any wave reaches iter t's barrier, so staging t+3 into buf[(t+3)&3]
// (= buf[(t-1)&3]) after that barrier is race-free.
template <typename OutT>
__global__ __launch_bounds__(512, 2)
void gemm256c(const unsigned short* __restrict__ A0,
              const unsigned short* __restrict__ W0, OutT* __restrict__ C0,
              const unsigned short* __restrict__ A1,
              const unsigned short* __restrict__ W1, OutT* __restrict__ C1,
              const unsigned short* __restrict__ A2,
              const unsigned short* __restrict__ W2, OutT* __restrict__ C2,
              int K, int N) {
  constexpr int BK = 32;
  __shared__ alignas(16) unsigned short As[4][256 * BK];
  __shared__ alignas(16) unsigned short Bs[4][256 * BK];
  const int z = blockIdx.z;
  const unsigned short* A = z == 0 ? A0 : (z == 1 ? A1 : A2);
  const unsigned short* W = z == 0 ? W0 : (z == 1 ? W1 : W2);
  OutT* C_out = z == 0 ? C0 : (z == 1 ? C1 : C2);
  // XCD-aware tile assignment (grid 64x4 per z; 256 % 8 == 0 -> bijective)
  const int h = (int)blockIdx.x + ((int)blockIdx.y << 6);
  const int m_idx = ((h & 7) << 3) | ((h >> 3) & 7);
  const int n_idx = h >> 6;
  const int m0 = m_idx * 256;
  const int n0 = n_idx * 256;
  const int tid = threadIdx.x;
  const int lane = tid & 63;
  const int w = tid >> 6;            // 0..7
  const int wm = w >> 2;             // 0..1  (row half)
  const int wn = w & 3;              // 0..3  (col quarter)
  const int fr = lane & 15;
  const int ksl = lane >> 4;         // 0..3: 16B k-slot

  f32x4 acc[8][4];
#pragma unroll
  for (int i = 0; i < 8; ++i)
#pragma unroll
    for (int j = 0; j < 4; ++j) acc[i][j] = (f32x4){0.f, 0.f, 0.f, 0.f};

  // Staging: per operand tile = 256 rows x 4 slots = 1024 x 16B chunks.
  // Wave w: chunks [w*128, w*128+128), 2 wave-loads per operand.
#define STAGE(buf, kt)                                                        \
  {                                                                           \
    _Pragma("unroll")                                                         \
    for (int cc = 0; cc < 2; ++cc) {                                          \
      const int c = w * 128 + cc * 64 + lane;                                 \
      const int row = c >> 2;                                                 \
      const int gsl = (c & 3) ^ ((row >> 1) & 3);                             \
      gload16(A + (size_t)(m0 + row) * K + (kt) + gsl * 8,                    \
              &As[buf][(size_t)c * 8]);                                       \
      gload16(W + (size_t)(n0 + row) * K + (kt) + gsl * 8,                    \
              &Bs[buf][(size_t)c * 8]);                                       \
    }                                                                         \
  }

#define LDSRD(bufp, row, sl) \
  (*(const short8*)&(bufp)[(row) * 32 + ((((sl) ^ (((row) >> 1) & 3))) * 8)])

  const int nt = K / BK;             // 32
  STAGE(0, 0);
  STAGE(1, BK);
  STAGE(2, 2 * BK);
  for (int t = 0; t < nt; ++t) {
    const int rem = nt - t;
    if (rem > 2)       asm volatile("s_waitcnt vmcnt(8)" ::: "memory");
    else if (rem == 2) asm volatile("s_waitcnt vmcnt(4)" ::: "memory");
    else               asm volatile("s_waitcnt vmcnt(0)" ::: "memory");
    __builtin_amdgcn_s_barrier();
    FENCE();
    if (t + 3 < nt) STAGE((t + 3) & 3, (t + 3) * BK);
    const unsigned short* Ab = As[t & 3];
    const unsigned short* Bb = Bs[t & 3];
    short8 af[8], bf[4];
#pragma unroll
    for (int i = 0; i < 8; ++i)
      af[i] = LDSRD(Ab, wm * 128 + i * 16 + fr, ksl);
#pragma unroll
    for (int j = 0; j < 4; ++j)
      bf[j] = LDSRD(Bb, wn * 64 + j * 16 + fr, ksl);
    __builtin_amdgcn_s_setprio(1);
#pragma unroll
    for (int i = 0; i < 8; ++i)
#pragma unroll
      for (int j = 0; j < 4; ++j)
        acc[i][j] = __builtin_amdgcn_mfma_f32_16x16x32_bf16(af[i], bf[j],
                                                            acc[i][j], 0, 0, 0);
    __builtin_amdgcn_s_setprio(0);
    FENCE();
  }
#undef STAGE
#undef LDSRD

  // C/D layout: col = lane&15, row = (lane>>4)*4 + q
  const int orow = (lane >> 4) * 4;
  const int ocol = lane & 15;
#pragma unroll
  for (int i = 0; i < 8; ++i)
#pragma unroll
    for (int j = 0; j < 4; ++j) {
      const size_t rbase = (size_t)(m0 + wm * 128 + i * 16 + orow);
      const int cb = n0 + wn * 64 + j * 16 + ocol;
#pragma unroll
      for (int q = 0; q < 4; ++q) {
        const float vq = acc[i][j][q];
        if constexpr (sizeof(OutT) == 2)
          C_out[(rbase + q) * N + cb] = (OutT)f2b(vq);
        else
          C_out[(rbase + q) * N + cb] = (OutT)vq;
      }
    }
}

// ---------------- WKV chunked scan (bf16 inputs) ----------------
__global__ void wkv_phase1(const unsigned short* __restrict__ keyb,
                           const unsigned short* __restrict__ valb,
                           const float* __restrict__ td,
                           float* __restrict__ s_num,
                           float* __restrict__ s_den,
                           float* __restrict__ s_mx) {
  const int g = blockIdx.x * blockDim.x + threadIdx.x;  // [0, B*NCH*C)
  const int c = g & (Cc - 1);
  const int j = (g / Cc) & (WKV_NCH - 1);
  const int b = g / (Cc * WKV_NCH);
  const float w = -__expf(td[c]);
  float num = 0.f, den = 0.f, mx = -1e38f;
  size_t idx = ((size_t)b * Tc + (size_t)j * WKV_L) * Cc + c;
#pragma unroll 4
  for (int i = 0; i < WKV_L; ++i, idx += Cc) {
    const float kt = b2f(keyb[idx]);
    const float vt = b2f(valb[idx]);
    const float mw = mx + w;
    const float mn = fmaxf(mw, kt);
    const float a1 = __expf(mw - mn);
    const float a2 = __expf(kt - mn);
    num = a1 * num + a2 * vt;
    den = a1 * den + a2;
    mx = mn;
  }
  s_num[g] = num; s_den[g] = den; s_mx[g] = mx;
}

__global__ void wkv_phase2(const float* __restrict__ td,
                           float* __restrict__ s_num,
                           float* __restrict__ s_den,
                           float* __restrict__ s_mx) {
  const int g = blockIdx.x * blockDim.x + threadIdx.x;  // [0, B*C)
  const int c = g & (Cc - 1);
  const int b = g / Cc;
  const float Lw = -__expf(td[c]) * (float)WKV_L;
  float num = 0.f, den = 0.f, mx = -1e38f;
  size_t base = (size_t)b * WKV_NCH * Cc + c;
  for (int j = 0; j < WKV_NCH; ++j) {
    const size_t s = base + (size_t)j * Cc;
    const float ln = s_num[s], ld = s_den[s], lm = s_mx[s];
    s_num[s] = num; s_den[s] = den; s_mx[s] = mx;  // exclusive prefix
    const float md = mx + Lw;
    const float m = fmaxf(md, lm);
    const float e1 = __expf(md - m);
    const float e2 = __expf(lm - m);
    num = e1 * num + e2 * ln;
    den = e1 * den + e2 * ld;
    mx = m;
  }
}

__global__ void wkv_phase3(const unsigned short* __restrict__ keyb,
                           const unsigned short* __restrict__ valb,
                           const unsigned short* __restrict__ recb,
                           const float* __restrict__ td,
                           const float* __restrict__ tf,
                           const float* __restrict__ s_num,
                           const float* __restrict__ s_den,
                           const float* __restrict__ s_mx,
                           unsigned short* __restrict__ rwkv) {
  const int g = blockIdx.x * blockDim.x + threadIdx.x;  // [0, B*NCH*C)
  const int c = g & (Cc - 1);
  const int j = (g / Cc) & (WKV_NCH - 1);
  const int b = g / (Cc * WKV_NCH);
  const float w = -__expf(td[c]);
  const float u = tf[c];
  float num = s_num[g], den = s_den[g], mx = s_mx[g];
  size_t idx = ((size_t)b * Tc + (size_t)j * WKV_L) * Cc + c;
#pragma unroll 2
  for (int i = 0; i < WKV_L; ++i, idx += Cc) {
    const float kt = b2f(keyb[idx]);
    const float vt = b2f(valb[idx]);
    const float rt = b2f(recb[idx]);
    const float ku = kt + u;
    const float mo = fmaxf(mx, ku);
    const float e1 = __expf(mx - mo);
    const float e2 = __expf(ku - mo);
    const float out = (e1 * num + e2 * vt) / (e1 * den + e2);
    const float sr = 1.f / (1.f + __expf(-rt));
    rwkv[idx] = f2b(sr * out);
    const float mw = mx + w;
    const float mn = fmaxf(mw, kt);
    const float a1 = __expf(mw - mn);
    const float a2 = __expf(kt - mn);
    num = a1 * num + a2 * vt;
    den = a1 * den + a2;
    mx = mn;
  }
}

extern "C" void kernel_launch(void* const* d_in, const int* in_sizes, int n_in,
                              void* d_out, int out_size, void* d_ws, size_t ws_size,
                              hipStream_t stream) {
  const float* x   = (const float*)d_in[0];
  const float* Wk  = (const float*)d_in[1];
  const float* Wv  = (const float*)d_in[2];
  const float* Wr  = (const float*)d_in[3];
  const float* Wo  = (const float*)d_in[4];
  const float* td  = (const float*)d_in[5];
  const float* tf  = (const float*)d_in[6];
  const float* tmk = (const float*)d_in[7];
  const float* tmv = (const float*)d_in[8];
  const float* tmr = (const float*)d_in[9];

  const long BT = (long)Bc * Tc;     // 16384
  const long NE = BT * Cc;           // 16,777,216
  const long CC = (long)Cc * Cc;     // 1,048,576

  // Workspace carve (~200 MB)
  char* p = (char*)d_ws;
  unsigned short* Wk_b = (unsigned short*)p; p += CC * 2;
  unsigned short* Wv_b = (unsigned short*)p; p += CC * 2;
  unsigned short* Wr_b = (unsigned short*)p; p += CC * 2;
  unsigned short* Wo_b = (unsigned short*)p; p += CC * 2;
  unsigned short* kin  = (unsigned short*)p; p += NE * 2;
  unsigned short* vin  = (unsigned short*)p; p += NE * 2;
  unsigned short* rin  = (unsigned short*)p; p += NE * 2;
  unsigned short* keyb = (unsigned short*)p; p += NE * 2;
  unsigned short* valb = (unsigned short*)p; p += NE * 2;
  unsigned short* recb = (unsigned short*)p; p += NE * 2;
  // aliases: rwkv reuses kin (dead after key GEMM); s_* reuse vin (dead after
  // value GEMM). 3 x 2MB well within vin's 32MB.
  unsigned short* rwkv = kin;
  const long NS = (long)Bc * WKV_NCH * Cc;  // 524288
  float* s_num = (float*)vin;
  float* s_den = s_num + NS;
  float* s_mx  = s_den + NS;

  // 1. weights -> bf16 (single dispatch)
  {
    dim3 g((unsigned)(CC / 4 / 256), 4), b_(256);
    convert4_kernel<<<g, b_, 0, stream>>>(Wk, Wv, Wr, Wo,
                                          Wk_b, Wv_b, Wr_b, Wo_b);
  }

  // 2. time-mix + cast
  mix3_kernel<<<2048, 256, 0, stream>>>(x, tmk, tmv, tmr, kin, vin, rin, NE / 4);

  // 3. K/V/R GEMMs (K=1024), batched via blockIdx.z, bf16 outputs
  {
    dim3 grid((unsigned)(BT / 256), (unsigned)(Cc / 256), 3), blk(512);
    gemm256c<unsigned short><<<grid, blk, 0, stream>>>(
        kin, Wk_b, keyb, vin, Wv_b, valb, rin, Wr_b, recb, Cc, Cc);
  }

  // 4. WKV chunked scan + sigmoid gate -> rwkv bf16
  wkv_phase1<<<2048, 256, 0, stream>>>(keyb, valb, td, s_num, s_den, s_mx);
  wkv_phase2<<<32, 256, 0, stream>>>(td, s_num, s_den, s_mx);
  wkv_phase3<<<2048, 256, 0, stream>>>(keyb, valb, recb, td, tf,
                                       s_num, s_den, s_mx, rwkv);

  // 5. output GEMM -> d_out (f32)
  {
    dim3 grid((unsigned)(BT / 256), (unsigned)(Cc / 256), 1), blk(512);
    gemm256c<float><<<grid, blk, 0, stream>>>(
        rwkv, Wo_b, (float*)d_out, rwkv, Wo_b, (float*)d_out,
        rwkv, Wo_b, (float*)d_out, Cc, Cc);
  }
}

// Round 9
// 279.228 us; speedup vs baseline: 1.0113x; 1.0113x over previous
//
#include <hip/hip_runtime.h>
#include <cstdint>
#include <cstddef>

#define DEVI __device__ __forceinline__

typedef __attribute__((ext_vector_type(8))) short short8;
typedef __attribute__((ext_vector_type(4))) float f32x4;

constexpr int Bc = 8, Tc = 2048, Cc = 1024;
constexpr int WKV_L = 32, WKV_NCH = 64;   // T = L * NCH

DEVI unsigned short f2b(float f) {
  unsigned int u = __float_as_uint(f);
  unsigned int r = (u + 0x7FFFu + ((u >> 16) & 1u)) >> 16;  // RNE
  return (unsigned short)r;
}
DEVI float b2f(unsigned short u) {
  return __uint_as_float(((unsigned int)u) << 16);
}

DEVI void gload16(const unsigned short* g, unsigned short* l) {
  __builtin_amdgcn_global_load_lds(
      (const __attribute__((address_space(1))) void*)g,
      (__attribute__((address_space(3))) void*)l, 16, 0, 0);
}

#define FENCE() asm volatile("" ::: "memory")

// ---------------- f32 -> bf16 convert (all 4 weights, one dispatch) --------
__global__ void convert4_kernel(const float* __restrict__ W0,
                                const float* __restrict__ W1,
                                const float* __restrict__ W2,
                                const float* __restrict__ W3,
                                unsigned short* __restrict__ o0,
                                unsigned short* __restrict__ o1,
                                unsigned short* __restrict__ o2,
                                unsigned short* __restrict__ o3) {
  const int i = blockIdx.x * blockDim.x + threadIdx.x;   // [0, CC/4)
  const int s = blockIdx.y;
  const float* in = s == 0 ? W0 : (s == 1 ? W1 : (s == 2 ? W2 : W3));
  unsigned short* out = s == 0 ? o0 : (s == 1 ? o1 : (s == 2 ? o2 : o3));
  const float4 v = ((const float4*)in)[i];
  ushort4 o;
  o.x = f2b(v.x); o.y = f2b(v.y); o.z = f2b(v.z); o.w = f2b(v.w);
  ((ushort4*)out)[i] = o;
}

// ---------------- time-mix (k,v,r) + bf16 cast ----------------
__global__ void mix3_kernel(const float* __restrict__ x,
                            const float* __restrict__ tmk,
                            const float* __restrict__ tmv,
                            const float* __restrict__ tmr,
                            unsigned short* __restrict__ kin,
                            unsigned short* __restrict__ vin,
                            unsigned short* __restrict__ rin,
                            long n4) {
  long i = (long)blockIdx.x * blockDim.x + threadIdx.x;
  const long stride = (long)gridDim.x * blockDim.x;
  for (; i < n4; i += stride) {
    const long e = i * 4;
    const int c = (int)(e & (Cc - 1));
    const long bt = e >> 10;
    const int t = (int)(bt & (Tc - 1));
    const float4 xv = *(const float4*)(x + e);
    float4 pv = {0.f, 0.f, 0.f, 0.f};
    if (t > 0) pv = *(const float4*)(x + e - Cc);
    const float4 mk = *(const float4*)(tmk + c);
    const float4 mv = *(const float4*)(tmv + c);
    const float4 mr = *(const float4*)(tmr + c);
    const float* xp = (const float*)&xv;
    const float* pp = (const float*)&pv;
    const float* mkp = (const float*)&mk;
    const float* mvp = (const float*)&mv;
    const float* mrp = (const float*)&mr;
    ushort4 ko, vo, ro;
    unsigned short* kop = (unsigned short*)&ko;
    unsigned short* vop = (unsigned short*)&vo;
    unsigned short* rop = (unsigned short*)&ro;
#pragma unroll
    for (int q = 0; q < 4; ++q) {
      kop[q] = f2b(xp[q] * mkp[q] + pp[q] * (1.f - mkp[q]));
      vop[q] = f2b(xp[q] * mvp[q] + pp[q] * (1.f - mvp[q]));
      rop[q] = f2b(xp[q] * mrp[q] + pp[q] * (1.f - mrp[q]));
    }
    *(ushort4*)(kin + e) = ko;
    *(ushort4*)(vin + e) = vo;
    *(ushort4*)(rin + e) = ro;
  }
}

// -------- 256x256 / BK=64 / 8-wave bf16 GEMM (R5-proven structure) ---------
// C[M][N] = A[M][K] * W[N][K]^T. blockIdx.z selects (A,W,C) triple.
// 2 LDS buffers, vmcnt(0)+barrier then STAGE(next) then bulk compute;
// XOR swizzle phys-slot = s ^ (row&7) via pre-swizzled global source
// (rule #21); verified 0 bank conflicts, MfmaUtil 33.5%, 808 TF (R5).
template <typename OutT>
__global__ __launch_bounds__(512, 2)
void gemm256(const unsigned short* __restrict__ A0,
             const unsigned short* __restrict__ W0, OutT* __restrict__ C0,
             const unsigned short* __restrict__ A1,
             const unsigned short* __restrict__ W1, OutT* __restrict__ C1,
             const unsigned short* __restrict__ A2,
             const unsigned short* __restrict__ W2, OutT* __restrict__ C2,
             int K, int N) {
  constexpr int BK = 64;
  __shared__ alignas(16) unsigned short As[2][256 * BK];
  __shared__ alignas(16) unsigned short Bs[2][256 * BK];
  const int z = blockIdx.z;
  const unsigned short* A = z == 0 ? A0 : (z == 1 ? A1 : A2);
  const unsigned short* W = z == 0 ? W0 : (z == 1 ? W1 : W2);
  OutT* C_out = z == 0 ? C0 : (z == 1 ? C1 : C2);
  const int m0 = blockIdx.x * 256;
  const int n0 = blockIdx.y * 256;
  const int tid = threadIdx.x;
  const int lane = tid & 63;
  const int w = tid >> 6;            // 0..7
  const int wm = w >> 2;             // 0..1  (row half)
  const int wn = w & 3;              // 0..3  (col quarter)
  const int fr = lane & 15;
  const int ksl = lane >> 4;         // 0..3: 8-elem k-subslot within 32

  f32x4 acc[8][4];
#pragma unroll
  for (int i = 0; i < 8; ++i)
#pragma unroll
    for (int j = 0; j < 4; ++j) acc[i][j] = (f32x4){0.f, 0.f, 0.f, 0.f};

#define STAGE(buf, kt)                                                        \
  {                                                                           \
    _Pragma("unroll")                                                         \
    for (int cc = 0; cc < 4; ++cc) {                                          \
      const int c = w * 256 + cc * 64 + lane;                                 \
      const int row = c >> 3;                                                 \
      const int gsl = (c & 7) ^ (row & 7);                                    \
      gload16(A + (size_t)(m0 + row) * K + (kt) + gsl * 8,                    \
              &As[buf][(w * 256 + cc * 64) * 8]);                             \
      gload16(W + (size_t)(n0 + row) * K + (kt) + gsl * 8,                    \
              &Bs[buf][(w * 256 + cc * 64) * 8]);                             \
    }                                                                         \
  }

  const int nt = K / BK;
  STAGE(0, 0);
  int cur = 0;
  for (int t = 0; t < nt; ++t) {
    asm volatile("s_waitcnt vmcnt(0)" ::: "memory");
    __builtin_amdgcn_s_barrier();   // collective: tile t ready; t-1 reads done
    FENCE();
    if (t + 1 < nt) STAGE(cur ^ 1, (t + 1) * BK);
#pragma unroll
    for (int ks = 0; ks < 2; ++ks) {
      const int sl = ks * 4 + ksl;   // logical 16B slot
      short8 af[8], bf[4];
#pragma unroll
      for (int i = 0; i < 8; ++i) {
        const int row = wm * 128 + i * 16 + fr;
        af[i] = *(const short8*)&As[cur][row * 64 + ((sl ^ (row & 7)) * 8)];
      }
#pragma unroll
      for (int j = 0; j < 4; ++j) {
        const int row = wn * 64 + j * 16 + fr;
        bf[j] = *(const short8*)&Bs[cur][row * 64 + ((sl ^ (row & 7)) * 8)];
      }
      __builtin_amdgcn_s_setprio(1);
#pragma unroll
      for (int i = 0; i < 8; ++i)
#pragma unroll
        for (int j = 0; j < 4; ++j)
          acc[i][j] = __builtin_amdgcn_mfma_f32_16x16x32_bf16(af[i], bf[j],
                                                              acc[i][j], 0, 0, 0);
      __builtin_amdgcn_s_setprio(0);
    }
    FENCE();
    cur ^= 1;
  }
#undef STAGE

  // C/D layout: col = lane&15, row = (lane>>4)*4 + q
  const int orow = (lane >> 4) * 4;
  const int ocol = lane & 15;
#pragma unroll
  for (int i = 0; i < 8; ++i)
#pragma unroll
    for (int j = 0; j < 4; ++j) {
      const size_t rbase = (size_t)(m0 + wm * 128 + i * 16 + orow);
      const int cb = n0 + wn * 64 + j * 16 + ocol;
#pragma unroll
      for (int q = 0; q < 4; ++q) {
        const float vq = acc[i][j][q];
        if constexpr (sizeof(OutT) == 2)
          C_out[(rbase + q) * N + cb] = (OutT)f2b(vq);
        else
          C_out[(rbase + q) * N + cb] = (OutT)vq;
      }
    }
}

// ---------------- WKV chunked scan, 4 channels/thread (vectorized) ---------
// Thread g: b = g>>14, j = (g>>8)&63, c4 = g&255 -> channels c4*4..c4*4+3.
// s_* layout [b][j][c]: float4 at g*4.

__global__ void wkv_phase1(const unsigned short* __restrict__ keyb,
                           const unsigned short* __restrict__ valb,
                           const float* __restrict__ td,
                           float* __restrict__ s_num,
                           float* __restrict__ s_den,
                           float* __restrict__ s_mx) {
  const int g = blockIdx.x * blockDim.x + threadIdx.x;  // [0, B*NCH*C/4)
  const int c4 = g & 255;
  const int j = (g >> 8) & (WKV_NCH - 1);
  const int b = g >> 14;
  const float4 td4 = *(const float4*)(td + c4 * 4);
  float w[4], num[4], den[4], mx[4];
#pragma unroll
  for (int q = 0; q < 4; ++q) {
    w[q] = -__expf(((const float*)&td4)[q]);
    num[q] = 0.f; den[q] = 0.f; mx[q] = -1e38f;
  }
  size_t off = ((size_t)b * Tc + (size_t)j * WKV_L) * Cc + c4 * 4;
#pragma unroll 4
  for (int i = 0; i < WKV_L; ++i, off += Cc) {
    const ushort4 k4 = *(const ushort4*)(keyb + off);
    const ushort4 v4 = *(const ushort4*)(valb + off);
    const unsigned short* kp = (const unsigned short*)&k4;
    const unsigned short* vp = (const unsigned short*)&v4;
#pragma unroll
    for (int q = 0; q < 4; ++q) {
      const float kt = b2f(kp[q]);
      const float vt = b2f(vp[q]);
      const float mw = mx[q] + w[q];
      const float mn = fmaxf(mw, kt);
      const float a1 = __expf(mw - mn);
      const float a2 = __expf(kt - mn);
      num[q] = a1 * num[q] + a2 * vt;
      den[q] = a1 * den[q] + a2;
      mx[q] = mn;
    }
  }
  *(float4*)(s_num + (size_t)g * 4) = *(float4*)num;
  *(float4*)(s_den + (size_t)g * 4) = *(float4*)den;
  *(float4*)(s_mx  + (size_t)g * 4) = *(float4*)mx;
}

__global__ void wkv_phase2(const float* __restrict__ td,
                           float* __restrict__ s_num,
                           float* __restrict__ s_den,
                           float* __restrict__ s_mx) {
  const int g = blockIdx.x * blockDim.x + threadIdx.x;  // [0, B*C/4)
  const int c4 = g & 255;
  const int b = g >> 8;
  const float4 td4 = *(const float4*)(td + c4 * 4);
  float Lw[4], num[4], den[4], mx[4];
#pragma unroll
  for (int q = 0; q < 4; ++q) {
    Lw[q] = -__expf(((const float*)&td4)[q]) * (float)WKV_L;
    num[q] = 0.f; den[q] = 0.f; mx[q] = -1e38f;
  }
  const size_t base = (size_t)b * WKV_NCH * Cc + c4 * 4;
  for (int j = 0; j < WKV_NCH; ++j) {
    const size_t s = base + (size_t)j * Cc;
    float4 ln4 = *(float4*)(s_num + s);
    float4 ld4 = *(float4*)(s_den + s);
    float4 lm4 = *(float4*)(s_mx + s);
    *(float4*)(s_num + s) = *(float4*)num;   // exclusive prefix
    *(float4*)(s_den + s) = *(float4*)den;
    *(float4*)(s_mx + s)  = *(float4*)mx;
#pragma unroll
    for (int q = 0; q < 4; ++q) {
      const float md = mx[q] + Lw[q];
      const float m = fmaxf(md, ((const float*)&lm4)[q]);
      const float e1 = __expf(md - m);
      const float e2 = __expf(((const float*)&lm4)[q] - m);
      num[q] = e1 * num[q] + e2 * ((const float*)&ln4)[q];
      den[q] = e1 * den[q] + e2 * ((const float*)&ld4)[q];
      mx[q] = m;
    }
  }
}

__global__ void wkv_phase3(const unsigned short* __restrict__ keyb,
                           const unsigned short* __restrict__ valb,
                           const unsigned short* __restrict__ recb,
                           const float* __restrict__ td,
                           const float* __restrict__ tf,
                           const float* __restrict__ s_num,
                           const float* __restrict__ s_den,
                           const float* __restrict__ s_mx,
                           unsigned short* __restrict__ rwkv) {
  const int g = blockIdx.x * blockDim.x + threadIdx.x;  // [0, B*NCH*C/4)
  const int c4 = g & 255;
  const int j = (g >> 8) & (WKV_NCH - 1);
  const int b = g >> 14;
  const float4 td4 = *(const float4*)(td + c4 * 4);
  const float4 tf4 = *(const float4*)(tf + c4 * 4);
  float w[4], num[4], den[4], mx[4];
  const float4 n4 = *(const float4*)(s_num + (size_t)g * 4);
  const float4 d4 = *(const float4*)(s_den + (size_t)g * 4);
  const float4 m4 = *(const float4*)(s_mx + (size_t)g * 4);
#pragma unroll
  for (int q = 0; q < 4; ++q) {
    w[q] = -__expf(((const float*)&td4)[q]);
    num[q] = ((const float*)&n4)[q];
    den[q] = ((const float*)&d4)[q];
    mx[q] = ((const float*)&m4)[q];
  }
  size_t off = ((size_t)b * Tc + (size_t)j * WKV_L) * Cc + c4 * 4;
#pragma unroll 2
  for (int i = 0; i < WKV_L; ++i, off += Cc) {
    const ushort4 k4 = *(const ushort4*)(keyb + off);
    const ushort4 v4 = *(const ushort4*)(valb + off);
    const ushort4 r4 = *(const ushort4*)(recb + off);
    const unsigned short* kp = (const unsigned short*)&k4;
    const unsigned short* vp = (const unsigned short*)&v4;
    const unsigned short* rp = (const unsigned short*)&r4;
    ushort4 o4;
    unsigned short* op = (unsigned short*)&o4;
#pragma unroll
    for (int q = 0; q < 4; ++q) {
      const float kt = b2f(kp[q]);
      const float vt = b2f(vp[q]);
      const float rt = b2f(rp[q]);
      const float ku = kt + ((const float*)&tf4)[q];
      const float mo = fmaxf(mx[q], ku);
      const float e1 = __expf(mx[q] - mo);
      const float e2 = __expf(ku - mo);
      const float out = (e1 * num[q] + e2 * vt) / (e1 * den[q] + e2);
      const float sr = 1.f / (1.f + __expf(-rt));
      op[q] = f2b(sr * out);
      const float mw = mx[q] + w[q];
      const float mn = fmaxf(mw, kt);
      const float a1 = __expf(mw - mn);
      const float a2 = __expf(kt - mn);
      num[q] = a1 * num[q] + a2 * vt;
      den[q] = a1 * den[q] + a2;
      mx[q] = mn;
    }
    *(ushort4*)(rwkv + off) = o4;
  }
}

extern "C" void kernel_launch(void* const* d_in, const int* in_sizes, int n_in,
                              void* d_out, int out_size, void* d_ws, size_t ws_size,
                              hipStream_t stream) {
  const float* x   = (const float*)d_in[0];
  const float* Wk  = (const float*)d_in[1];
  const float* Wv  = (const float*)d_in[2];
  const float* Wr  = (const float*)d_in[3];
  const float* Wo  = (const float*)d_in[4];
  const float* td  = (const float*)d_in[5];
  const float* tf  = (const float*)d_in[6];
  const float* tmk = (const float*)d_in[7];
  const float* tmv = (const float*)d_in[8];
  const float* tmr = (const float*)d_in[9];

  const long BT = (long)Bc * Tc;     // 16384
  const long NE = BT * Cc;           // 16,777,216
  const long CC = (long)Cc * Cc;     // 1,048,576

  // Workspace carve (~200 MB)
  char* p = (char*)d_ws;
  unsigned short* Wk_b = (unsigned short*)p; p += CC * 2;
  unsigned short* Wv_b = (unsigned short*)p; p += CC * 2;
  unsigned short* Wr_b = (unsigned short*)p; p += CC * 2;
  unsigned short* Wo_b = (unsigned short*)p; p += CC * 2;
  unsigned short* kin  = (unsigned short*)p; p += NE * 2;
  unsigned short* vin  = (unsigned short*)p; p += NE * 2;
  unsigned short* rin  = (unsigned short*)p; p += NE * 2;
  unsigned short* keyb = (unsigned short*)p; p += NE * 2;
  unsigned short* valb = (unsigned short*)p; p += NE * 2;
  unsigned short* recb = (unsigned short*)p; p += NE * 2;
  // aliases: rwkv reuses kin (dead after key GEMM); s_* reuse vin (dead after
  // value GEMM). 3 x 2MB well within vin's 32MB.
  unsigned short* rwkv = kin;
  const long NS = (long)Bc * WKV_NCH * Cc;  // 524288
  float* s_num = (float*)vin;
  float* s_den = s_num + NS;
  float* s_mx  = s_den + NS;

  // 1. weights -> bf16 (single dispatch)
  {
    dim3 g((unsigned)(CC / 4 / 256), 4), b_(256);
    convert4_kernel<<<g, b_, 0, stream>>>(Wk, Wv, Wr, Wo,
                                          Wk_b, Wv_b, Wr_b, Wo_b);
  }

  // 2. time-mix + cast
  mix3_kernel<<<2048, 256, 0, stream>>>(x, tmk, tmv, tmr, kin, vin, rin, NE / 4);

  // 3. K/V/R GEMMs (K=1024), batched via blockIdx.z, bf16 outputs
  {
    dim3 grid((unsigned)(BT / 256), (unsigned)(Cc / 256), 3), blk(512);
    gemm256<unsigned short><<<grid, blk, 0, stream>>>(
        kin, Wk_b, keyb, vin, Wv_b, valb, rin, Wr_b, recb, Cc, Cc);
  }

  // 4. WKV chunked scan + sigmoid gate -> rwkv bf16 (4 channels/thread)
  wkv_phase1<<<512, 256, 0, stream>>>(keyb, valb, td, s_num, s_den, s_mx);
  wkv_phase2<<<8, 256, 0, stream>>>(td, s_num, s_den, s_mx);
  wkv_phase3<<<512, 256, 0, stream>>>(keyb, valb, recb, td, tf,
                                      s_num, s_den, s_mx, rwkv);

  // 5. output GEMM -> d_out (f32)
  {
    dim3 grid((unsigned)(BT / 256), (unsigned)(Cc / 256), 1), blk(512);
    gemm256<float><<<grid, blk, 0, stream>>>(
        rwkv, Wo_b, (float*)d_out, rwkv, Wo_b, (float*)d_out,
        rwkv, Wo_b, (float*)d_out, Cc, Cc);
  }
}

// Round 10
// 267.783 us; speedup vs baseline: 1.0545x; 1.0427x over previous
//
#include <hip/hip_runtime.h>
#include <cstdint>
#include <cstddef>

#define DEVI __device__ __forceinline__

typedef __attribute__((ext_vector_type(8))) short short8;
typedef __attribute__((ext_vector_type(4))) float f32x4;

constexpr int Bc = 8, Tc = 2048, Cc = 1024;
constexpr int WKV_L = 32, WKV_NCH = 64;   // T = L * NCH

DEVI unsigned short f2b(float f) {
  unsigned int u = __float_as_uint(f);
  unsigned int r = (u + 0x7FFFu + ((u >> 16) & 1u)) >> 16;  // RNE
  return (unsigned short)r;
}
DEVI float b2f(unsigned short u) {
  return __uint_as_float(((unsigned int)u) << 16);
}

DEVI void gload16(const unsigned short* g, unsigned short* l) {
  __builtin_amdgcn_global_load_lds(
      (const __attribute__((address_space(1))) void*)g,
      (__attribute__((address_space(3))) void*)l, 16, 0, 0);
}

#define FENCE() asm volatile("" ::: "memory")

// ---------------- f32 -> bf16 convert (all 4 weights, one dispatch) --------
__global__ void convert4_kernel(const float* __restrict__ W0,
                                const float* __restrict__ W1,
                                const float* __restrict__ W2,
                                const float* __restrict__ W3,
                                unsigned short* __restrict__ o0,
                                unsigned short* __restrict__ o1,
                                unsigned short* __restrict__ o2,
                                unsigned short* __restrict__ o3) {
  const int i = blockIdx.x * blockDim.x + threadIdx.x;   // [0, CC/4)
  const int s = blockIdx.y;
  const float* in = s == 0 ? W0 : (s == 1 ? W1 : (s == 2 ? W2 : W3));
  unsigned short* out = s == 0 ? o0 : (s == 1 ? o1 : (s == 2 ? o2 : o3));
  const float4 v = ((const float4*)in)[i];
  ushort4 o;
  o.x = f2b(v.x); o.y = f2b(v.y); o.z = f2b(v.z); o.w = f2b(v.w);
  ((ushort4*)out)[i] = o;
}

// ---------------- time-mix (k,v,r) + bf16 cast ----------------
__global__ void mix3_kernel(const float* __restrict__ x,
                            const float* __restrict__ tmk,
                            const float* __restrict__ tmv,
                            const float* __restrict__ tmr,
                            unsigned short* __restrict__ kin,
                            unsigned short* __restrict__ vin,
                            unsigned short* __restrict__ rin,
                            long n4) {
  long i = (long)blockIdx.x * blockDim.x + threadIdx.x;
  const long stride = (long)gridDim.x * blockDim.x;
  for (; i < n4; i += stride) {
    const long e = i * 4;
    const int c = (int)(e & (Cc - 1));
    const long bt = e >> 10;
    const int t = (int)(bt & (Tc - 1));
    const float4 xv = *(const float4*)(x + e);
    float4 pv = {0.f, 0.f, 0.f, 0.f};
    if (t > 0) pv = *(const float4*)(x + e - Cc);
    const float4 mk = *(const float4*)(tmk + c);
    const float4 mv = *(const float4*)(tmv + c);
    const float4 mr = *(const float4*)(tmr + c);
    const float* xp = (const float*)&xv;
    const float* pp = (const float*)&pv;
    const float* mkp = (const float*)&mk;
    const float* mvp = (const float*)&mv;
    const float* mrp = (const float*)&mr;
    ushort4 ko, vo, ro;
    unsigned short* kop = (unsigned short*)&ko;
    unsigned short* vop = (unsigned short*)&vo;
    unsigned short* rop = (unsigned short*)&ro;
#pragma unroll
    for (int q = 0; q < 4; ++q) {
      kop[q] = f2b(xp[q] * mkp[q] + pp[q] * (1.f - mkp[q]));
      vop[q] = f2b(xp[q] * mvp[q] + pp[q] * (1.f - mvp[q]));
      rop[q] = f2b(xp[q] * mrp[q] + pp[q] * (1.f - mrp[q]));
    }
    *(ushort4*)(kin + e) = ko;
    *(ushort4*)(vin + e) = vo;
    *(ushort4*)(rin + e) = ro;
  }
}

// -------- 256x256 / BK=64 / 8-wave bf16 GEMM, chunk-pipelined inner loop ----
// C[M][N] = A[M][K] * W[N][K]^T. blockIdx.z selects (A,W,C) triple.
// Sync structure identical to R5 (proven): vmcnt(0)+barrier at top, STAGE
// after barrier, XOR swizzle phys-slot = s ^ (row&7) via pre-swizzled global
// source (0 conflicts verified). NEW: the 24 ds_reads / 64 MFMAs per tile are
// split into 4 chunks; reads of chunk p+1 are issued BEFORE MFMAs of chunk p
// (named register sets, static indexing) so the DS pipe runs under the MFMA
// pipe instead of serializing. No setprio in the loop.
template <typename OutT>
__global__ __launch_bounds__(512, 2)
void gemm256(const unsigned short* __restrict__ A0,
             const unsigned short* __restrict__ W0, OutT* __restrict__ C0,
             const unsigned short* __restrict__ A1,
             const unsigned short* __restrict__ W1, OutT* __restrict__ C1,
             const unsigned short* __restrict__ A2,
             const unsigned short* __restrict__ W2, OutT* __restrict__ C2,
             int K, int N) {
  constexpr int BK = 64;
  __shared__ alignas(16) unsigned short As[2][256 * BK];
  __shared__ alignas(16) unsigned short Bs[2][256 * BK];
  const int z = blockIdx.z;
  const unsigned short* A = z == 0 ? A0 : (z == 1 ? A1 : A2);
  const unsigned short* W = z == 0 ? W0 : (z == 1 ? W1 : W2);
  OutT* C_out = z == 0 ? C0 : (z == 1 ? C1 : C2);
  const int m0 = blockIdx.x * 256;
  const int n0 = blockIdx.y * 256;
  const int tid = threadIdx.x;
  const int lane = tid & 63;
  const int w = tid >> 6;            // 0..7
  const int wm = w >> 2;             // 0..1  (row half)
  const int wn = w & 3;              // 0..3  (col quarter)
  const int fr = lane & 15;
  const int ksl = lane >> 4;         // 0..3: 8-elem k-subslot within 32

  f32x4 acc[8][4];
#pragma unroll
  for (int i = 0; i < 8; ++i)
#pragma unroll
    for (int j = 0; j < 4; ++j) acc[i][j] = (f32x4){0.f, 0.f, 0.f, 0.f};

#define STAGE(buf, kt)                                                        \
  {                                                                           \
    _Pragma("unroll")                                                         \
    for (int cc = 0; cc < 4; ++cc) {                                          \
      const int c = w * 256 + cc * 64 + lane;                                 \
      const int row = c >> 3;                                                 \
      const int gsl = (c & 7) ^ (row & 7);                                    \
      gload16(A + (size_t)(m0 + row) * K + (kt) + gsl * 8,                    \
              &As[buf][(w * 256 + cc * 64) * 8]);                             \
      gload16(W + (size_t)(n0 + row) * K + (kt) + gsl * 8,                    \
              &Bs[buf][(w * 256 + cc * 64) * 8]);                             \
    }                                                                         \
  }

#define LDSRD(bufp, row, sl) \
  (*(const short8*)&(bufp)[(row) * 64 + ((((sl) ^ ((row) & 7))) * 8)])

  const int nt = K / BK;
  STAGE(0, 0);
  int cur = 0;
  for (int t = 0; t < nt; ++t) {
    asm volatile("s_waitcnt vmcnt(0)" ::: "memory");
    __builtin_amdgcn_s_barrier();   // collective: tile t ready; t-1 reads done
    FENCE();
    if (t + 1 < nt) STAGE(cur ^ 1, (t + 1) * BK);
    const unsigned short* Ab = As[cur];
    const unsigned short* Bb = Bs[cur];
    const int sl0 = ksl;            // logical 16B slot, k-slice 0
    const int sl1 = 4 + ksl;        // k-slice 1
    short8 a0[4], b0[4], a1g[4], a2g[4], b2[4], a3[4];
    // chunk0 reads: A rows 0-63 @ks0, B @ks0
#pragma unroll
    for (int i = 0; i < 4; ++i)
      a0[i] = LDSRD(Ab, wm * 128 + i * 16 + fr, sl0);
#pragma unroll
    for (int j = 0; j < 4; ++j)
      b0[j] = LDSRD(Bb, wn * 64 + j * 16 + fr, sl0);
    // chunk1 reads: A rows 64-127 @ks0
#pragma unroll
    for (int i = 0; i < 4; ++i)
      a1g[i] = LDSRD(Ab, wm * 128 + (4 + i) * 16 + fr, sl0);
    // MFMA chunk0
#pragma unroll
    for (int i = 0; i < 4; ++i)
#pragma unroll
      for (int j = 0; j < 4; ++j)
        acc[i][j] = __builtin_amdgcn_mfma_f32_16x16x32_bf16(a0[i], b0[j],
                                                            acc[i][j], 0, 0, 0);
    // chunk2 reads: A rows 0-63 @ks1, B @ks1
#pragma unroll
    for (int i = 0; i < 4; ++i)
      a2g[i] = LDSRD(Ab, wm * 128 + i * 16 + fr, sl1);
#pragma unroll
    for (int j = 0; j < 4; ++j)
      b2[j] = LDSRD(Bb, wn * 64 + j * 16 + fr, sl1);
    // MFMA chunk1
#pragma unroll
    for (int i = 0; i < 4; ++i)
#pragma unroll
      for (int j = 0; j < 4; ++j)
        acc[4 + i][j] = __builtin_amdgcn_mfma_f32_16x16x32_bf16(a1g[i], b0[j],
                                                                acc[4 + i][j], 0, 0, 0);
    // chunk3 reads: A rows 64-127 @ks1
#pragma unroll
    for (int i = 0; i < 4; ++i)
      a3[i] = LDSRD(Ab, wm * 128 + (4 + i) * 16 + fr, sl1);
    // MFMA chunk2
#pragma unroll
    for (int i = 0; i < 4; ++i)
#pragma unroll
      for (int j = 0; j < 4; ++j)
        acc[i][j] = __builtin_amdgcn_mfma_f32_16x16x32_bf16(a2g[i], b2[j],
                                                            acc[i][j], 0, 0, 0);
    // MFMA chunk3
#pragma unroll
    for (int i = 0; i < 4; ++i)
#pragma unroll
      for (int j = 0; j < 4; ++j)
        acc[4 + i][j] = __builtin_amdgcn_mfma_f32_16x16x32_bf16(a3[i], b2[j],
                                                                acc[4 + i][j], 0, 0, 0);
    FENCE();
    cur ^= 1;
  }
#undef STAGE
#undef LDSRD

  // C/D layout: col = lane&15, row = (lane>>4)*4 + q
  const int orow = (lane >> 4) * 4;
  const int ocol = lane & 15;
#pragma unroll
  for (int i = 0; i < 8; ++i)
#pragma unroll
    for (int j = 0; j < 4; ++j) {
      const size_t rbase = (size_t)(m0 + wm * 128 + i * 16 + orow);
      const int cb = n0 + wn * 64 + j * 16 + ocol;
#pragma unroll
      for (int q = 0; q < 4; ++q) {
        const float vq = acc[i][j][q];
        if constexpr (sizeof(OutT) == 2)
          C_out[(rbase + q) * N + cb] = (OutT)f2b(vq);
        else
          C_out[(rbase + q) * N + cb] = (OutT)vq;
      }
    }
}

// ---------------- WKV chunked scan (1 ch/thread, single-exp updates) -------
// Update uses one exp: mn = max(mw,kt); the larger side's factor is exactly 1,
// the other is exp(-|mw-kt|) -> bit-identical to the two-exp form.
__global__ void wkv_phase1(const unsigned short* __restrict__ keyb,
                           const unsigned short* __restrict__ valb,
                           const float* __restrict__ td,
                           float* __restrict__ s_num,
                           float* __restrict__ s_den,
                           float* __restrict__ s_mx) {
  const int g = blockIdx.x * blockDim.x + threadIdx.x;  // [0, B*NCH*C)
  const int c = g & (Cc - 1);
  const int j = (g / Cc) & (WKV_NCH - 1);
  const int b = g / (Cc * WKV_NCH);
  const float w = -__expf(td[c]);
  float num = 0.f, den = 0.f, mx = -1e38f;
  size_t idx = ((size_t)b * Tc + (size_t)j * WKV_L) * Cc + c;
#pragma unroll 4
  for (int i = 0; i < WKV_L; ++i, idx += Cc) {
    const float kt = b2f(keyb[idx]);
    const float vt = b2f(valb[idx]);
    const float mw = mx + w;
    const bool cg = mw >= kt;
    const float d = __expf(cg ? kt - mw : mw - kt);
    const float a1 = cg ? 1.f : d;
    const float a2 = cg ? d : 1.f;
    num = a1 * num + a2 * vt;
    den = a1 * den + a2;
    mx = cg ? mw : kt;
  }
  s_num[g] = num; s_den[g] = den; s_mx[g] = mx;
}

__global__ void wkv_phase2(const float* __restrict__ td,
                           float* __restrict__ s_num,
                           float* __restrict__ s_den,
                           float* __restrict__ s_mx) {
  const int g = blockIdx.x * blockDim.x + threadIdx.x;  // [0, B*C)
  const int c = g & (Cc - 1);
  const int b = g / Cc;
  const float Lw = -__expf(td[c]) * (float)WKV_L;
  float num = 0.f, den = 0.f, mx = -1e38f;
  size_t base = (size_t)b * WKV_NCH * Cc + c;
  for (int j = 0; j < WKV_NCH; ++j) {
    const size_t s = base + (size_t)j * Cc;
    const float ln = s_num[s], ld = s_den[s], lm = s_mx[s];
    s_num[s] = num; s_den[s] = den; s_mx[s] = mx;  // exclusive prefix
    const float md = mx + Lw;
    const bool cg = md >= lm;
    const float d = __expf(cg ? lm - md : md - lm);
    const float e1 = cg ? 1.f : d;
    const float e2 = cg ? d : 1.f;
    num = e1 * num + e2 * ln;
    den = e1 * den + e2 * ld;
    mx = cg ? md : lm;
  }
}

__global__ void wkv_phase3(const unsigned short* __restrict__ keyb,
                           const unsigned short* __restrict__ valb,
                           const unsigned short* __restrict__ recb,
                           const float* __restrict__ td,
                           const float* __restrict__ tf,
                           const float* __restrict__ s_num,
                           const float* __restrict__ s_den,
                           const float* __restrict__ s_mx,
                           unsigned short* __restrict__ rwkv) {
  const int g = blockIdx.x * blockDim.x + threadIdx.x;  // [0, B*NCH*C)
  const int c = g & (Cc - 1);
  const int j = (g / Cc) & (WKV_NCH - 1);
  const int b = g / (Cc * WKV_NCH);
  const float w = -__expf(td[c]);
  const float u = tf[c];
  float num = s_num[g], den = s_den[g], mx = s_mx[g];
  size_t idx = ((size_t)b * Tc + (size_t)j * WKV_L) * Cc + c;
#pragma unroll 2
  for (int i = 0; i < WKV_L; ++i, idx += Cc) {
    const float kt = b2f(keyb[idx]);
    const float vt = b2f(valb[idx]);
    const float rt = b2f(recb[idx]);
    const float ku = kt + u;
    const bool co = mx >= ku;
    const float dd = __expf(co ? ku - mx : mx - ku);
    const float e1 = co ? 1.f : dd;
    const float e2 = co ? dd : 1.f;
    const float out = (e1 * num + e2 * vt) / (e1 * den + e2);
    const float sr = 1.f / (1.f + __expf(-rt));
    rwkv[idx] = f2b(sr * out);
    const float mw = mx + w;
    const bool cg = mw >= kt;
    const float du = __expf(cg ? kt - mw : mw - kt);
    const float a1 = cg ? 1.f : du;
    const float a2 = cg ? du : 1.f;
    num = a1 * num + a2 * vt;
    den = a1 * den + a2;
    mx = cg ? mw : kt;
  }
}

extern "C" void kernel_launch(void* const* d_in, const int* in_sizes, int n_in,
                              void* d_out, int out_size, void* d_ws, size_t ws_size,
                              hipStream_t stream) {
  const float* x   = (const float*)d_in[0];
  const float* Wk  = (const float*)d_in[1];
  const float* Wv  = (const float*)d_in[2];
  const float* Wr  = (const float*)d_in[3];
  const float* Wo  = (const float*)d_in[4];
  const float* td  = (const float*)d_in[5];
  const float* tf  = (const float*)d_in[6];
  const float* tmk = (const float*)d_in[7];
  const float* tmv = (const float*)d_in[8];
  const float* tmr = (const float*)d_in[9];

  const long BT = (long)Bc * Tc;     // 16384
  const long NE = BT * Cc;           // 16,777,216
  const long CC = (long)Cc * Cc;     // 1,048,576

  // Workspace carve (~200 MB)
  char* p = (char*)d_ws;
  unsigned short* Wk_b = (unsigned short*)p; p += CC * 2;
  unsigned short* Wv_b = (unsigned short*)p; p += CC * 2;
  unsigned short* Wr_b = (unsigned short*)p; p += CC * 2;
  unsigned short* Wo_b = (unsigned short*)p; p += CC * 2;
  unsigned short* kin  = (unsigned short*)p; p += NE * 2;
  unsigned short* vin  = (unsigned short*)p; p += NE * 2;
  unsigned short* rin  = (unsigned short*)p; p += NE * 2;
  unsigned short* keyb = (unsigned short*)p; p += NE * 2;
  unsigned short* valb = (unsigned short*)p; p += NE * 2;
  unsigned short* recb = (unsigned short*)p; p += NE * 2;
  // aliases: rwkv reuses kin (dead after key GEMM); s_* reuse vin (dead after
  // value GEMM). 3 x 2MB well within vin's 32MB.
  unsigned short* rwkv = kin;
  const long NS = (long)Bc * WKV_NCH * Cc;  // 524288
  float* s_num = (float*)vin;
  float* s_den = s_num + NS;
  float* s_mx  = s_den + NS;

  // 1. weights -> bf16 (single dispatch)
  {
    dim3 g((unsigned)(CC / 4 / 256), 4), b_(256);
    convert4_kernel<<<g, b_, 0, stream>>>(Wk, Wv, Wr, Wo,
                                          Wk_b, Wv_b, Wr_b, Wo_b);
  }

  // 2. time-mix + cast
  mix3_kernel<<<2048, 256, 0, stream>>>(x, tmk, tmv, tmr, kin, vin, rin, NE / 4);

  // 3. K/V/R GEMMs (K=1024), batched via blockIdx.z, bf16 outputs
  {
    dim3 grid((unsigned)(BT / 256), (unsigned)(Cc / 256), 3), blk(512);
    gemm256<unsigned short><<<grid, blk, 0, stream>>>(
        kin, Wk_b, keyb, vin, Wv_b, valb, rin, Wr_b, recb, Cc, Cc);
  }

  // 4. WKV chunked scan + sigmoid gate -> rwkv bf16
  wkv_phase1<<<2048, 256, 0, stream>>>(keyb, valb, td, s_num, s_den, s_mx);
  wkv_phase2<<<32, 256, 0, stream>>>(td, s_num, s_den, s_mx);
  wkv_phase3<<<2048, 256, 0, stream>>>(keyb, valb, recb, td, tf,
                                       s_num, s_den, s_mx, rwkv);

  // 5. output GEMM -> d_out (f32)
  {
    dim3 grid((unsigned)(BT / 256), (unsigned)(Cc / 256), 1), blk(512);
    gemm256<float><<<grid, blk, 0, stream>>>(
        rwkv, Wo_b, (float*)d_out, rwkv, Wo_b, (float*)d_out,
        rwkv, Wo_b, (float*)d_out, Cc, Cc);
  }
}